// Round 7
// baseline (5970.858 us; speedup 1.0000x reference)
//
#include <hip/hip_runtime.h>
#include <hip/hip_bf16.h>

#define SEQ    256
#define BATCH  64
#define HID    1024
#define G4     4096
#define NWG    256
#define NTH    512

typedef __bf16 bf16x8 __attribute__((ext_vector_type(8)));
typedef float  f32x4  __attribute__((ext_vector_type(4)));
typedef unsigned short u16;

__device__ __forceinline__ u16 f2bf(float f) {
    unsigned int u = __float_as_uint(f);
    unsigned int r = (u + 0x7fffu + ((u >> 16) & 1u)) >> 16;  // RNE
    return (u16)r;
}
__device__ __forceinline__ float sigmoid_f(float x) {
    x = fminf(fmaxf(x, -30.f), 30.f);
    return 1.f / (1.f + __expf(-x));
}
__device__ __forceinline__ float tanh_f(float x) {
    x = fminf(fmaxf(x, -15.f), 15.f);
    float e2 = __expf(2.f * x);
    return (e2 - 1.f) / (e2 + 1.f);
}

// ---------------- prep: fp32->bf16 for x and Wx; zero flags ----------------
__global__ void prep_kernel(const float* __restrict__ x, u16* __restrict__ Xbf,
                            const float* __restrict__ Wx, u16* __restrict__ WxBf,
                            int* __restrict__ flags) {
    int idx = blockIdx.x * blockDim.x + threadIdx.x;
    if (idx < 1024)
        __hip_atomic_store(flags + idx, 0, __ATOMIC_RELAXED, __HIP_MEMORY_SCOPE_AGENT);
    int stride = gridDim.x * blockDim.x;
    int nx4 = SEQ * BATCH * HID / 4;
    const float4* in4 = (const float4*)x;
    ushort4* out4 = (ushort4*)Xbf;
    for (int i = idx; i < nx4; i += stride) {
        float4 v = in4[i];
        ushort4 o; o.x = f2bf(v.x); o.y = f2bf(v.y); o.z = f2bf(v.z); o.w = f2bf(v.w);
        out4[i] = o;
    }
    int nw4 = 2 * G4 * HID / 4;
    const float4* w4 = (const float4*)Wx;
    ushort4* wo4 = (ushort4*)WxBf;
    for (int i = idx; i < nw4; i += stride) {
        float4 v = w4[i];
        ushort4 o; o.x = f2bf(v.x); o.y = f2bf(v.y); o.z = f2bf(v.z); o.w = f2bf(v.w);
        wo4[i] = o;
    }
}

// ---- region barrier: 64 WGs; each writes own flag, wave0 polls 64 flags ----
__device__ __forceinline__ void region_signal(int* rf, int wl, int fid) {
    asm volatile("s_waitcnt vmcnt(0)" ::: "memory");  // sc-stores visible at L3
    __syncthreads();
    if (threadIdx.x == 0)
        __hip_atomic_store(rf + wl, fid, __ATOMIC_RELAXED, __HIP_MEMORY_SCOPE_AGENT);
}
__device__ __forceinline__ void region_poll(const int* rf, int fid) {
    if (threadIdx.x < 64) {
        for (;;) {
            int v = __hip_atomic_load(rf + (int)threadIdx.x, __ATOMIC_RELAXED,
                                      __HIP_MEMORY_SCOPE_AGENT);
            if (__all(v >= fid)) break;
            __builtin_amdgcn_s_sleep(1);
        }
    }
    __syncthreads();
}

#define SCLD(dst, base, OFFS) \
    asm volatile("global_load_dwordx4 %0, %1, off offset:" OFFS " sc0 sc1" \
                 : "=v"(dst) : "v"(base))
#define SCLD32(a, base) do { \
    SCLD(a[ 0],base,   "0"); SCLD(a[ 1],base,  "64"); SCLD(a[ 2],base, "128"); SCLD(a[ 3],base, "192"); \
    SCLD(a[ 4],base, "256"); SCLD(a[ 5],base, "320"); SCLD(a[ 6],base, "384"); SCLD(a[ 7],base, "448"); \
    SCLD(a[ 8],base, "512"); SCLD(a[ 9],base, "576"); SCLD(a[10],base, "640"); SCLD(a[11],base, "704"); \
    SCLD(a[12],base, "768"); SCLD(a[13],base, "832"); SCLD(a[14],base, "896"); SCLD(a[15],base, "960"); \
    SCLD(a[16],base,"1024"); SCLD(a[17],base,"1088"); SCLD(a[18],base,"1152"); SCLD(a[19],base,"1216"); \
    SCLD(a[20],base,"1280"); SCLD(a[21],base,"1344"); SCLD(a[22],base,"1408"); SCLD(a[23],base,"1472"); \
    SCLD(a[24],base,"1536"); SCLD(a[25],base,"1600"); SCLD(a[26],base,"1664"); SCLD(a[27],base,"1728"); \
    SCLD(a[28],base,"1792"); SCLD(a[29],base,"1856"); SCLD(a[30],base,"1920"); SCLD(a[31],base,"1984"); \
} while (0)

// 1-tile x-GEMM, plain (L2-cached) A and B
__device__ __forceinline__ f32x4 xgemm_plain(const u16* __restrict__ A, const u16* __restrict__ B) {
    f32x4 acc = {0.f,0.f,0.f,0.f};
    #pragma unroll
    for (int ks = 0; ks < 32; ++ks)
        acc = __builtin_amdgcn_mfma_f32_16x16x32_bf16(*(const bf16x8*)(A + ks * 32),
                                                      *(const bf16x8*)(B + ks * 32), acc, 0, 0, 0);
    return acc;
}

// 1-tile x-GEMM, sc-loads for A (Y0 cross-XCD), plain B
__device__ __forceinline__ f32x4 xgemm_sc(const u16* A, const u16* __restrict__ B) {
    bf16x8 xf[32];
    SCLD32(xf, A);
    asm volatile("s_waitcnt vmcnt(0)" ::: "memory");
    __builtin_amdgcn_sched_barrier(0);
    f32x4 acc = {0.f,0.f,0.f,0.f};
    #pragma unroll
    for (int ks = 0; ks < 32; ++ks)
        acc = __builtin_amdgcn_mfma_f32_16x16x32_bf16(xf[ks], *(const bf16x8*)(B + ks * 32), acc, 0, 0, 0);
    return acc;
}

// ---------------- layer-pipelined persistent LSTM, 512-thread WGs ----------------
// bid: role=bid>>7 (layer), grp=(bid>>6)&1 (rows grp*32..+32), wl=bid&63 (16 h-cols).
// wave w=tid>>6: gate=w&3, rowhalf rh=w>>2 -> one 16x16 tile each. L1 lags L0 (one-way poll).
__global__ void __launch_bounds__(NTH, 2) lstm_coop(
    const u16* __restrict__ Xbf,   // [SEQ][BATCH][HID] bf16
    u16* __restrict__ Y0bf,        // [SEQ][BATCH][HID] bf16 (L0 out, sc-accessed)
    const u16* __restrict__ WxBf,  // [2][4096][1024] bf16
    u16* __restrict__ hbuf,        // [4 regions][2][32][HID] bf16 (sc-accessed)
    int* __restrict__ flags,       // [4][64]
    const float* __restrict__ h0,
    const float* __restrict__ c0,
    const float* __restrict__ Wh,  // [2][4096][1024] fp32
    const float* __restrict__ bx,
    const float* __restrict__ bh,
    float* __restrict__ out)       // ys | hT | cT
{
    __shared__ u16   WhL[4][16384];       // per-gate Wh tile, fragment order
    __shared__ float gbuf[4 * 32 * 17];   // [gate][row 0..31][col 0..15], padded

    const int bid  = blockIdx.x;
    const int role = bid >> 7;
    const int grp  = (bid >> 6) & 1;
    const int wl   = bid & 63;
    const int hc0  = wl * 16;
    const int tid  = threadIdx.x;
    const int w    = tid >> 6;
    const int gate = w & 3;
    const int rh   = w >> 2;
    const int lane = tid & 63;
    const int fr   = lane & 15;
    const int fg   = lane >> 4;
    const int b_l  = tid >> 4;     // cell row 0..31
    const int c_l  = tid & 15;     // cell col 0..15

    const int region = role * 2 + grp;
    int*       ownf  = flags + region * 64;
    const int* prodf = flags + grp * 64;          // L0 region, same batch group

    u16* hbase = hbuf + (size_t)region * 2 * 32 * HID;

    float* ys = out;
    float* hT = out + (size_t)SEQ * BATCH * HID;
    float* cT = hT + (size_t)2 * BATCH * HID;

    // ---- stage Wh (own layer) into LDS, fragment order; wave rh stages half the k-range ----
    {
        size_t rowg = (size_t)role * G4 + (size_t)gate * 1024 + hc0 + fr;
        const float* src = Wh + rowg * HID + fg * 8;
        u16* dst = &WhL[gate][lane * 8];
        #pragma unroll 4
        for (int kk = 0; kk < 16; ++kk) {
            int ks = rh * 16 + kk;
            float4 w0 = *(const float4*)(src + ks * 32);
            float4 w1 = *(const float4*)(src + ks * 32 + 4);
            ushort4 o0, o1;
            o0.x = f2bf(w0.x); o0.y = f2bf(w0.y); o0.z = f2bf(w0.z); o0.w = f2bf(w0.w);
            o1.x = f2bf(w1.x); o1.y = f2bf(w1.y); o1.z = f2bf(w1.z); o1.w = f2bf(w1.w);
            *(ushort4*)(dst + ks * 512)     = o0;
            *(ushort4*)(dst + ks * 512 + 4) = o1;
        }
    }
    const float bias_v = bx[role * G4 + gate * 1024 + hc0 + fr]
                       + bh[role * G4 + gate * 1024 + hc0 + fr];

    // ---- init h (sc-stores, buffer 0) and per-thread c ----
    {
        float hv = h0[((size_t)role * BATCH + grp * 32 + b_l) * HID + hc0 + c_l];
        u16* hdst = hbase + (size_t)b_l * HID + hc0 + c_l;
        unsigned int hv32 = f2bf(hv);
        asm volatile("global_store_short %0, %1, off sc0 sc1" :: "v"(hdst), "v"(hv32) : "memory");
    }
    float c_reg = c0[((size_t)role * BATCH + grp * 32 + b_l) * HID + hc0 + c_l];

    region_signal(ownf, wl, 1);
    region_poll(ownf, 1);

    const u16* WxB = WxBf + ((size_t)role * G4 + (size_t)gate * 1024 + hc0 + fr) * HID + fg * 8;
    const size_t xr = ((size_t)grp * 32 + rh * 16 + fr) * HID + fg * 8;

    f32x4 accx;
    if (role == 0) {
        accx = xgemm_plain(Xbf + xr, WxB);
    } else {
        region_poll(prodf, 2);              // Y0(0) ready
        accx = xgemm_sc(Y0bf + xr, WxB);
    }

    int cur = 0;
    float h_out = 0.f;

    for (int t = 0; t < SEQ; ++t) {
        // ---- h-GEMM: 32 sc-loads, one wait, 32 MFMAs (B from LDS) ----
        const u16* hb = hbase + (size_t)cur * 32 * HID + (size_t)(rh * 16 + fr) * HID + fg * 8;
        bf16x8 hf[32];
        SCLD32(hf, hb);
        asm volatile("s_waitcnt vmcnt(0)" ::: "memory");
        __builtin_amdgcn_sched_barrier(0);
        f32x4 acc = accx;
        const u16* Bh = &WhL[gate][lane * 8];
        #pragma unroll
        for (int ks = 0; ks < 32; ++ks)
            acc = __builtin_amdgcn_mfma_f32_16x16x32_bf16(hf[ks], *(const bf16x8*)(Bh + ks * 512), acc, 0, 0, 0);

        // ---- gates -> gbuf (cross-wave exchange) ----
        #pragma unroll
        for (int i = 0; i < 4; ++i)
            gbuf[(gate * 32 + rh * 16 + fg * 4 + i) * 17 + fr] = acc[i] + bias_v;
        __syncthreads();

        // ---- cell update: thread (b_l, c_l) ----
        float gi = gbuf[(0 * 32 + b_l) * 17 + c_l];
        float gf = gbuf[(1 * 32 + b_l) * 17 + c_l];
        float gg = gbuf[(2 * 32 + b_l) * 17 + c_l];
        float go = gbuf[(3 * 32 + b_l) * 17 + c_l];
        c_reg = sigmoid_f(gf) * c_reg + sigmoid_f(gi) * tanh_f(gg);
        h_out = sigmoid_f(go) * tanh_f(c_reg);

        unsigned int hbv = f2bf(h_out);
        {
            u16* d0 = hbase + (size_t)(cur ^ 1) * 32 * HID + (size_t)b_l * HID + hc0 + c_l;
            asm volatile("global_store_short %0, %1, off sc0 sc1" :: "v"(d0), "v"(hbv) : "memory");
        }
        if (role == 0) {
            u16* y0 = Y0bf + ((size_t)t * BATCH + grp * 32 + b_l) * HID + hc0 + c_l;
            asm volatile("global_store_short %0, %1, off sc0 sc1" :: "v"(y0), "v"(hbv) : "memory");
        } else {
            ys[((size_t)t * BATCH + grp * 32 + b_l) * HID + hc0 + c_l] = h_out;
        }

        // ---- pipelined barrier: signal, prefetch next x/Y0, poll ----
        int fid = t + 2;
        region_signal(ownf, wl, fid);
        if (t < SEQ - 1) {
            if (role == 0) {
                accx = xgemm_plain(Xbf + (size_t)(t + 1) * BATCH * HID + xr, WxB);
            } else {
                region_poll(prodf, t + 3);   // L0 finished step t+1
                accx = xgemm_sc(Y0bf + (size_t)(t + 1) * BATCH * HID + xr, WxB);
            }
        }
        region_poll(ownf, fid);
        cur ^= 1;
    }

    hT[((size_t)role * BATCH + grp * 32 + b_l) * HID + hc0 + c_l] = h_out;
    cT[((size_t)role * BATCH + grp * 32 + b_l) * HID + hc0 + c_l] = c_reg;
}

extern "C" void kernel_launch(void* const* d_in, const int* in_sizes, int n_in,
                              void* d_out, int out_size, void* d_ws, size_t ws_size,
                              hipStream_t stream) {
    const float* x  = (const float*)d_in[0];
    const float* h0 = (const float*)d_in[1];
    const float* c0 = (const float*)d_in[2];
    const float* Wx = (const float*)d_in[3];
    const float* bx = (const float*)d_in[4];
    const float* Wh = (const float*)d_in[5];
    const float* bh = (const float*)d_in[6];
    float* out = (float*)d_out;

    u16* Xbf  = (u16*)d_ws;                                    // 16.78M elems
    u16* Y0bf = Xbf  + (size_t)SEQ * BATCH * HID;              // 16.78M elems
    u16* WxBf = Y0bf + (size_t)SEQ * BATCH * HID;              // 8.39M elems
    u16* hbuf = WxBf + (size_t)2 * G4 * HID;                   // 262144 elems
    int* flags = (int*)(hbuf + (size_t)4 * 2 * 32 * HID);

    prep_kernel<<<dim3(1024), dim3(256), 0, stream>>>(x, Xbf, Wx, WxBf, flags);

    void* args[] = {(void*)&Xbf, (void*)&Y0bf, (void*)&WxBf, (void*)&hbuf, (void*)&flags,
                    (void*)&h0, (void*)&c0, (void*)&Wh, (void*)&bx, (void*)&bh, (void*)&out};
    hipError_t err = hipLaunchCooperativeKernel((void*)lstm_coop, dim3(NWG), dim3(NTH),
                                                args, 0, stream);
    if (err != hipSuccess) {
        (void)hipGetLastError();   // clear sticky error; co-residency still holds (1 blk/CU, 256 CUs)
        lstm_coop<<<dim3(NWG), dim3(NTH), 0, stream>>>(Xbf, Y0bf, WxBf, hbuf, flags,
                                                       h0, c0, Wh, bx, bh, out);
    }
}